// Round 5
// baseline (382.130 us; speedup 1.0000x reference)
//
#include <hip/hip_runtime.h>
#include <cstddef>

typedef _Float16 h2 __attribute__((ext_vector_type(2)));
typedef unsigned int uint32;

// ---------------- tap geometry (compile-time) ----------------
// merged 17x17 kernel nonzeros: union of
//   even 9x9 grid (dil2 9x9 + dil4 3x3), 5x5 center (dil1), dil5 3x3, dil7 3x3
__host__ __device__ constexpr bool is_tap(int dy, int dx) {
  const bool ev = ((dy & 1) == 0) && ((dx & 1) == 0);
  const bool c5 = (dy >= -2 && dy <= 2 && dx >= -2 && dx <= 2);
  const bool d5 = ((dy == -5 || dy == 0 || dy == 5) && (dx == -5 || dx == 0 || dx == 5));
  const bool d7 = ((dy == -7 || dy == 0 || dy == 7) && (dx == -7 || dx == 0 || dx == 7));
  return ev || c5 || d5 || d7;
}

// 68 dot2-ops: each covers tap (dyt,dx) [weight .x] and, if bot, (dyt+2,dx) [.y].
struct OpT { int dyt, dx, bot; };
struct OpsTab { OpT v[68]; };
__host__ __device__ constexpr OpsTab make_ops() {
  OpsTab t{};
  int n = 0;
  // even-grid windows: dyt = -8,-4,0,4 (pairs with dyt+2), dyt=8 (singles)
  for (int g = 0; g < 5; ++g)
    for (int b = 0; b < 9; ++b)
      t.v[n++] = OpT{4 * g - 8, 2 * b - 8, g < 4 ? 1 : 0};
  // mixed ops, grouped by ascending dyt (window shared within group)
  t.v[n++] = {-7,-7,0}; t.v[n++] = {-7, 0,1}; t.v[n++] = {-7, 7,0};
  t.v[n++] = {-5,-5,0}; t.v[n++] = {-5, 5,0};
  t.v[n++] = {-2,-1,1}; t.v[n++] = {-2, 1,1};
  t.v[n++] = {-1,-2,1}; t.v[n++] = {-1,-1,1}; t.v[n++] = {-1, 0,1};
  t.v[n++] = {-1, 1,1}; t.v[n++] = {-1, 2,1};
  t.v[n++] = { 0,-7,0}; t.v[n++] = { 0,-5,0}; t.v[n++] = { 0, 5,0}; t.v[n++] = { 0, 7,0};
  t.v[n++] = { 2,-1,0}; t.v[n++] = { 2, 1,0};
  t.v[n++] = { 5,-5,0}; t.v[n++] = { 5, 0,1}; t.v[n++] = { 5, 5,0};
  t.v[n++] = { 7,-7,0}; t.v[n++] = { 7, 7,0};
  return t;
}
constexpr OpsTab OPS = make_ops();
__constant__ OpsTab g_OPS = make_ops();   // runtime-indexed copy for prep kernel

// compile-time proof: every tap covered exactly once, no non-tap touched
constexpr bool verify_ops() {
  int cnt[17][17] = {};
  for (int i = 0; i < 68; ++i) {
    const OpT& o = OPS.v[i];
    cnt[o.dyt + 8][o.dx + 8]++;
    if (o.bot) cnt[o.dyt + 10][o.dx + 8]++;
  }
  for (int dy = -8; dy <= 8; ++dy)
    for (int dx = -8; dx <= 8; ++dx)
      if (cnt[dy + 8][dx + 8] != (is_tap(dy, dx) ? 1 : 0)) return false;
  return true;
}
static_assert(verify_ops(), "tap coverage broken");

__device__ __forceinline__ float fdot2f(h2 a, h2 b, float c) {
#if __has_builtin(__builtin_amdgcn_fdot2)
  return __builtin_amdgcn_fdot2(a, b, c, false);
#else
  return fmaf((float)a[0], (float)b[0], fmaf((float)a[1], (float)b[1], c));
#endif
}

// ---------------- prep kernel: synthesize merged 17x17 kernels ----------------
struct BranchP {
  int ksz, scale, CIN, HID, COUT, S, nd;
  int dils[3];
  const float *dw_w, *dw_b, *w1, *b1, *w2, *b2, *dilw;
};

__device__ void run_branch(int tid, const BranchP P,
                           const float* w0, float* merged,
                           float* bufA, float* bufB) {
  const int S = P.S, ksz = P.ksz, CIN = P.CIN, HID = P.HID, COUT = P.COUT;
  const int SS = S * S;
  // 1) pad (bottom/right) + pixel_unshuffle (scale==1 -> copy)
  for (int i = tid; i < CIN * SS; i += 256) {
    const int cc = i / SS, rem = i % SS, hh = rem / S, ww = rem % S;
    const int s2 = P.scale * P.scale;
    const int c = cc / s2, r2 = cc % s2, si = r2 / P.scale, sj = r2 % P.scale;
    const int sh = hh * P.scale + si, sw = ww * P.scale + sj;
    bufA[i] = (sh < 17 && sw < 17) ? w0[c * 289 + sh * 17 + sw] : 0.f;
  }
  __syncthreads();
  // 2) depthwise 3x3, pad 1
  for (int i = tid; i < CIN * SS; i += 256) {
    const int ch = i / SS, rem = i % SS, y = rem / S, x = rem % S;
    float acc = P.dw_b[ch];
    for (int u = 0; u < 3; ++u)
      for (int v = 0; v < 3; ++v) {
        const int yy = y + u - 1, xx = x + v - 1;
        if (yy >= 0 && yy < S && xx >= 0 && xx < S)
          acc += bufA[ch * SS + yy * S + xx] * P.dw_w[ch * 9 + u * 3 + v];
      }
    bufB[i] = acc;
  }
  __syncthreads();
  // 3) 1x1 + bias + relu  (bufB -> bufA)
  for (int i = tid; i < HID * SS; i += 256) {
    const int ho = i / SS, rem = i % SS;
    float acc = P.b1[ho];
    for (int ci = 0; ci < CIN; ++ci) acc += bufB[ci * SS + rem] * P.w1[ho * CIN + ci];
    bufA[i] = fmaxf(acc, 0.f);
  }
  __syncthreads();
  // 4) 1x1 + bias  (bufA -> bufB)
  for (int i = tid; i < COUT * SS; i += 256) {
    const int po = i / SS, rem = i % SS;
    float acc = P.b2[po];
    for (int ci = 0; ci < HID; ++ci) acc += bufA[ci * SS + rem] * P.w2[po * HID + ci];
    bufB[i] = acc;
  }
  __syncthreads();
  // 5) bilinear S -> ksz  (bufB -> bufA)
  for (int i = tid; i < COUT * ksz * ksz; i += 256) {
    const int c = i / (ksz * ksz), rem = i % (ksz * ksz), oy = rem / ksz, ox = rem % ksz;
    const float ratio = (float)S / (float)ksz;
    float sy = fminf(fmaxf((oy + 0.5f) * ratio - 0.5f, 0.f), (float)(S - 1));
    float sx = fminf(fmaxf((ox + 0.5f) * ratio - 0.5f, 0.f), (float)(S - 1));
    const int y0 = (int)sy; const int y1 = min(y0 + 1, S - 1); const float ty = sy - (float)y0;
    const int x0 = (int)sx; const int x1 = min(x0 + 1, S - 1); const float tx = sx - (float)x0;
    const float* img = bufB + c * SS;
    const float top = img[y0 * S + x0] * (1.f - tx) + img[y0 * S + x1] * tx;
    const float bot = img[y1 * S + x0] * (1.f - tx) + img[y1 * S + x1] * tx;
    bufA[i] = top * (1.f - ty) + bot * ty;
  }
  __syncthreads();
  // 6) per-dil channel mix + zero-interleave + accumulate into merged
  for (int di = 0; di < P.nd; ++di) {
    const int d = P.dils[di];
    const int e = d * (ksz - 1) + 1, pp = 8 - e / 2;
    for (int i = tid; i < 3 * ksz * ksz; i += 256) {
      const int p = i / (ksz * ksz), rem = i % (ksz * ksz), ih = rem / ksz, iw = rem % ksz;
      float acc = 0.f;
      for (int c2 = 0; c2 < COUT; ++c2)
        acc += bufA[c2 * ksz * ksz + rem] * P.dilw[(di * 3 + p) * COUT + c2];
      merged[p * 289 + (pp + d * ih) * 17 + (pp + d * iw)] += acc;
    }
  }
  __syncthreads();
}

__global__ __launch_bounds__(256) void prep_kernel(
    const float* __restrict__ A1, const float* __restrict__ B1,
    const float* __restrict__ A2, const float* __restrict__ B2,
    const float* __restrict__ A3, const float* __restrict__ B3,
    const float* __restrict__ dw_w3, const float* __restrict__ dw_b3,
    const float* __restrict__ w1_3, const float* __restrict__ b1_3,
    const float* __restrict__ w2_3, const float* __restrict__ b2_3,
    const float* __restrict__ dilw3,
    const float* __restrict__ dw_w5, const float* __restrict__ dw_b5,
    const float* __restrict__ w1_5, const float* __restrict__ b1_5,
    const float* __restrict__ w2_5, const float* __restrict__ b2_5,
    const float* __restrict__ dilw5,
    const float* __restrict__ dw_w9, const float* __restrict__ dw_b9,
    const float* __restrict__ w1_9, const float* __restrict__ b1_9,
    const float* __restrict__ w2_9, const float* __restrict__ b2_9,
    const float* __restrict__ dilw9,
    uint32* __restrict__ wkp) {
  const int o = blockIdx.x;
  const int tid = threadIdx.x;
  __shared__ float w0[3 * 289];
  __shared__ float merged[3 * 289];
  __shared__ float bufA[3888];
  __shared__ float bufB[3888];

  // weight0[o,c] = A_c[o] (17x4) @ B_c[o] (4x17)
  for (int i = tid; i < 3 * 289; i += 256) {
    const int c = i / 289, rem = i % 289, k = rem / 17, l = rem % 17;
    const float* A = (c == 0 ? A1 : (c == 1 ? A2 : A3)) + o * 68;
    const float* B = (c == 0 ? B1 : (c == 1 ? B2 : B3)) + o * 68;
    float s = 0.f;
    for (int r = 0; r < 4; ++r) s += A[k * 4 + r] * B[r * 17 + l];
    w0[i] = s;
    merged[i] = 0.f;
  }
  __syncthreads();

  {
    BranchP P{3, 4, 48, 64, 12, 5, 3, {4, 5, 7}, dw_w3, dw_b3, w1_3, b1_3, w2_3, b2_3, dilw3};
    run_branch(tid, P, w0, merged, bufA, bufB);
  }
  {
    BranchP P{5, 2, 12, 48, 6, 9, 1, {1, 0, 0}, dw_w5, dw_b5, w1_5, b1_5, w2_5, b2_5, dilw5};
    run_branch(tid, P, w0, merged, bufA, bufB);
  }
  {
    BranchP P{9, 1, 3, 12, 3, 17, 1, {2, 0, 0}, dw_w9, dw_b9, w1_9, b1_9, w2_9, b2_9, dilw9};
    run_branch(tid, P, w0, merged, bufA, bufB);
  }

  // pack paired f16 weights: wkp[o][op][p] = h2(w[dyt][dx], bot ? w[dyt+2][dx] : 0)
  for (int i = tid; i < 68 * 3; i += 256) {
    const int op = i / 3, p = i - op * 3;
    const OpT t = g_OPS.v[op];
    const float top = merged[p * 289 + (t.dyt + 8) * 17 + (t.dx + 8)];
    const float bot = t.bot ? merged[p * 289 + (t.dyt + 10) * 17 + (t.dx + 8)] : 0.f;
    h2 hw;
    hw[0] = (_Float16)top;   // RTE
    hw[1] = (_Float16)bot;
    wkp[((size_t)o * 68 + op) * 3 + p] = __builtin_bit_cast(uint32, hw);
  }
}

// ---------------- main conv kernel ----------------
// out[n][c*3+p][y][x] = sum_taps merged[c][p][dy][dx] * x[n][c][y+dy][x+dx]
// block: (yt, c, n); 256 threads = 16 tx * 16 ty; thread: 1 row x 16 cols x 3 p
//
// LDS holds f16x2 vertical pairs: xt2[r][col] = (x[r][col], x[r+2][col]).
// Each dot2-op consumes one window row and a pre-paired weight (w_top, w_bot);
// v_dot2_f32_f16 does 2 MACs/inst with fp32 accumulation.
//
// XOR swizzle on the 4B-unit index (bits [4:2] ^= bits [7:5]): with 64B lane
// stride, 16 tx lanes land 2-per-16B-unit -> conflict-free-equivalent.
#define XTS(i) ((i) ^ ((((i) >> 5) & 7) << 2))

__global__ __launch_bounds__(256) void conv17_kernel(
    const float* __restrict__ xin, const uint32* __restrict__ wkp,
    float* __restrict__ out) {
  const int yt = blockIdx.x;   // 0..15 (16-row stripes)
  const int ch = blockIdx.y;   // 0..63
  const int n  = blockIdx.z;   // 0..7
  const int tid = threadIdx.x;

  __shared__ __align__(128) uint32 xt2[32 * 272];  // f16x2 pairs, rows y0-8..y0+23

  const float* xim = xin + ((size_t)(n * 64 + ch)) * 65536;
  const uint32* __restrict__ wch = wkp + (size_t)ch * (68 * 3);  // block-uniform -> s_load
  const int y0 = yt * 16;

  // load tile: each 4-col unit reads rows gy and gy+2, packs f16x2 pairs
  for (int i = tid; i < 32 * 68; i += 256) {
    const int r = i / 68, c4 = i % 68;
    const int gy = y0 - 8 + r;
    const int gc = c4 * 4 - 8;
    float4 a = make_float4(0.f, 0.f, 0.f, 0.f);
    float4 b = make_float4(0.f, 0.f, 0.f, 0.f);
    const bool colok = (c4 >= 2 && c4 <= 65);
    if (colok && gy >= 0 && gy < 256)      a = *(const float4*)(xim + gy * 256 + gc);
    if (colok && gy + 2 >= 0 && gy + 2 < 256) b = *(const float4*)(xim + (gy + 2) * 256 + gc);
    uint4 u;
    u.x = __builtin_bit_cast(uint32, __builtin_amdgcn_cvt_pkrtz(a.x, b.x));
    u.y = __builtin_bit_cast(uint32, __builtin_amdgcn_cvt_pkrtz(a.y, b.y));
    u.z = __builtin_bit_cast(uint32, __builtin_amdgcn_cvt_pkrtz(a.z, b.z));
    u.w = __builtin_bit_cast(uint32, __builtin_amdgcn_cvt_pkrtz(a.w, b.w));
    *(uint4*)&xt2[XTS(r * 272 + c4 * 4)] = u;
  }
  __syncthreads();

  const int tx = tid & 15, ty = tid >> 4;
  const int x0 = tx * 16;        // output cols [x0, x0+16), in 4B units == cols

  float acc[3][16] = {};
  h2 W[32];                      // window: cols x0-8 .. x0+23 (f16x2 pairs)

#define LOADWIN(trow) do {                                                  \
    const int rbase_ = (trow) * 272 + x0;                                   \
    _Pragma("unroll")                                                       \
    for (int q_ = 0; q_ < 8; ++q_) {                                        \
      const uint4 u_ = *(const uint4*)&xt2[XTS(rbase_ + 4 * q_)];           \
      W[4 * q_ + 0] = __builtin_bit_cast(h2, u_.x);                         \
      W[4 * q_ + 1] = __builtin_bit_cast(h2, u_.y);                         \
      W[4 * q_ + 2] = __builtin_bit_cast(h2, u_.z);                         \
      W[4 * q_ + 3] = __builtin_bit_cast(h2, u_.w);                         \
    }                                                                       \
  } while (0)

#define DOT_OP(dxc, wi) do {                                                \
    const uint32 w0_ = wch[(wi) * 3 + 0];                                   \
    const uint32 w1_ = wch[(wi) * 3 + 1];                                   \
    const uint32 w2_ = wch[(wi) * 3 + 2];                                   \
    _Pragma("unroll")                                                       \
    for (int j_ = 0; j_ < 16; ++j_) {                                       \
      const h2 xv_ = W[8 + (dxc) + j_];                                     \
      acc[0][j_] = fdot2f(xv_, __builtin_bit_cast(h2, w0_), acc[0][j_]);    \
      acc[1][j_] = fdot2f(xv_, __builtin_bit_cast(h2, w1_), acc[1][j_]);    \
      acc[2][j_] = fdot2f(xv_, __builtin_bit_cast(h2, w2_), acc[2][j_]);    \
    }                                                                       \
  } while (0)

  // ---- even-grid windows (rolled): dyt = 4g-8, ops g*9+b ----
  #pragma unroll 1
  for (int g = 0; g < 5; ++g) {
    LOADWIN(ty + 4 * g);
    #pragma unroll
    for (int b = 0; b < 9; ++b) DOT_OP(2 * b - 8, g * 9 + b);
  }

  // ---- mixed ops (unrolled; window load at dyt-group boundaries) ----
  #pragma unroll
  for (int m = 45; m < 68; ++m) {
    if (m == 45 || OPS.v[m].dyt != OPS.v[m - 1].dyt)
      LOADWIN(ty + OPS.v[m].dyt + 8);
    DOT_OP(OPS.v[m].dx, m);
  }

  // ---- store ----
  const int gy = y0 + ty;
  #pragma unroll
  for (int p = 0; p < 3; ++p) {
    float* op = out + (((size_t)n * 192 + ch * 3 + p) * 256 + gy) * 256 + x0;
    #pragma unroll
    for (int q = 0; q < 4; ++q)
      *(float4*)(op + 4 * q) = make_float4(acc[p][4 * q + 0], acc[p][4 * q + 1],
                                           acc[p][4 * q + 2], acc[p][4 * q + 3]);
  }
#undef LOADWIN
#undef DOT_OP
}

// ---------------- launch ----------------
extern "C" void kernel_launch(void* const* d_in, const int* in_sizes, int n_in,
                              void* d_out, int out_size, void* d_ws, size_t ws_size,
                              hipStream_t stream) {
  const float* xin = (const float*)d_in[0];
  const float* A1 = (const float*)d_in[1];
  const float* B1 = (const float*)d_in[2];
  const float* A2 = (const float*)d_in[3];
  const float* B2 = (const float*)d_in[4];
  const float* A3 = (const float*)d_in[5];
  const float* B3 = (const float*)d_in[6];
  const float* dw_w3 = (const float*)d_in[7];
  const float* dw_b3 = (const float*)d_in[8];
  const float* w1_3 = (const float*)d_in[9];
  const float* b1_3 = (const float*)d_in[10];
  const float* w2_3 = (const float*)d_in[11];
  const float* b2_3 = (const float*)d_in[12];
  const float* dilw3 = (const float*)d_in[13];
  const float* dw_w5 = (const float*)d_in[14];
  const float* dw_b5 = (const float*)d_in[15];
  const float* w1_5 = (const float*)d_in[16];
  const float* b1_5 = (const float*)d_in[17];
  const float* w2_5 = (const float*)d_in[18];
  const float* b2_5 = (const float*)d_in[19];
  const float* dilw5 = (const float*)d_in[20];
  const float* dw_w9 = (const float*)d_in[21];
  const float* dw_b9 = (const float*)d_in[22];
  const float* w1_9 = (const float*)d_in[23];
  const float* b1_9 = (const float*)d_in[24];
  const float* w2_9 = (const float*)d_in[25];
  const float* b2_9 = (const float*)d_in[26];
  const float* dilw9 = (const float*)d_in[27];

  uint32* wkp = (uint32*)d_ws;  // 64 * 68 * 3 * 4B = 52,224 B

  prep_kernel<<<64, 256, 0, stream>>>(
      A1, B1, A2, B2, A3, B3,
      dw_w3, dw_b3, w1_3, b1_3, w2_3, b2_3, dilw3,
      dw_w5, dw_b5, w1_5, b1_5, w2_5, b2_5, dilw5,
      dw_w9, dw_b9, w1_9, b1_9, w2_9, b2_9, dilw9,
      wkp);

  dim3 grid(16, 64, 8);
  conv17_kernel<<<grid, 256, 0, stream>>>(xin, wkp, (float*)d_out);
}

// Round 7
// 309.478 us; speedup vs baseline: 1.2348x; 1.2348x over previous
//
#include <hip/hip_runtime.h>
#include <cstddef>

typedef _Float16 h8 __attribute__((ext_vector_type(8)));
typedef float f4 __attribute__((ext_vector_type(4)));
typedef unsigned int uint32;

// ---------------- prep kernel: synthesize merged 17x17 kernels ----------------
struct BranchP {
  int ksz, scale, CIN, HID, COUT, S, nd;
  int dils[3];
  const float *dw_w, *dw_b, *w1, *b1, *w2, *b2, *dilw;
};

__device__ void run_branch(int tid, const BranchP P,
                           const float* w0, float* merged,
                           float* bufA, float* bufB) {
  const int S = P.S, ksz = P.ksz, CIN = P.CIN, HID = P.HID, COUT = P.COUT;
  const int SS = S * S;
  // 1) pad (bottom/right) + pixel_unshuffle (scale==1 -> copy)
  for (int i = tid; i < CIN * SS; i += 256) {
    const int cc = i / SS, rem = i % SS, hh = rem / S, ww = rem % S;
    const int s2 = P.scale * P.scale;
    const int c = cc / s2, r2 = cc % s2, si = r2 / P.scale, sj = r2 % P.scale;
    const int sh = hh * P.scale + si, sw = ww * P.scale + sj;
    bufA[i] = (sh < 17 && sw < 17) ? w0[c * 289 + sh * 17 + sw] : 0.f;
  }
  __syncthreads();
  // 2) depthwise 3x3, pad 1
  for (int i = tid; i < CIN * SS; i += 256) {
    const int ch = i / SS, rem = i % SS, y = rem / S, x = rem % S;
    float acc = P.dw_b[ch];
    for (int u = 0; u < 3; ++u)
      for (int v = 0; v < 3; ++v) {
        const int yy = y + u - 1, xx = x + v - 1;
        if (yy >= 0 && yy < S && xx >= 0 && xx < S)
          acc += bufA[ch * SS + yy * S + xx] * P.dw_w[ch * 9 + u * 3 + v];
      }
    bufB[i] = acc;
  }
  __syncthreads();
  // 3) 1x1 + bias + relu  (bufB -> bufA)
  for (int i = tid; i < HID * SS; i += 256) {
    const int ho = i / SS, rem = i % SS;
    float acc = P.b1[ho];
    for (int ci = 0; ci < CIN; ++ci) acc += bufB[ci * SS + rem] * P.w1[ho * CIN + ci];
    bufA[i] = fmaxf(acc, 0.f);
  }
  __syncthreads();
  // 4) 1x1 + bias  (bufA -> bufB)
  for (int i = tid; i < COUT * SS; i += 256) {
    const int po = i / SS, rem = i % SS;
    float acc = P.b2[po];
    for (int ci = 0; ci < HID; ++ci) acc += bufA[ci * SS + rem] * P.w2[po * HID + ci];
    bufB[i] = acc;
  }
  __syncthreads();
  // 5) bilinear S -> ksz  (bufB -> bufA)
  for (int i = tid; i < COUT * ksz * ksz; i += 256) {
    const int c = i / (ksz * ksz), rem = i % (ksz * ksz), oy = rem / ksz, ox = rem % ksz;
    const float ratio = (float)S / (float)ksz;
    float sy = fminf(fmaxf((oy + 0.5f) * ratio - 0.5f, 0.f), (float)(S - 1));
    float sx = fminf(fmaxf((ox + 0.5f) * ratio - 0.5f, 0.f), (float)(S - 1));
    const int y0 = (int)sy; const int y1 = min(y0 + 1, S - 1); const float ty = sy - (float)y0;
    const int x0 = (int)sx; const int x1 = min(x0 + 1, S - 1); const float tx = sx - (float)x0;
    const float* img = bufB + c * SS;
    const float top = img[y0 * S + x0] * (1.f - tx) + img[y0 * S + x1] * tx;
    const float bot = img[y1 * S + x0] * (1.f - tx) + img[y1 * S + x1] * tx;
    bufA[i] = top * (1.f - ty) + bot * ty;
  }
  __syncthreads();
  // 6) per-dil channel mix + zero-interleave + accumulate into merged
  for (int di = 0; di < P.nd; ++di) {
    const int d = P.dils[di];
    const int e = d * (ksz - 1) + 1, pp = 8 - e / 2;
    for (int i = tid; i < 3 * ksz * ksz; i += 256) {
      const int p = i / (ksz * ksz), rem = i % (ksz * ksz), ih = rem / ksz, iw = rem % ksz;
      float acc = 0.f;
      for (int c2 = 0; c2 < COUT; ++c2)
        acc += bufA[c2 * ksz * ksz + rem] * P.dilw[(di * 3 + p) * COUT + c2];
      merged[p * 289 + (pp + d * ih) * 17 + (pp + d * iw)] += acc;
    }
  }
  __syncthreads();
}

// A-matrix geometry: K = 17 dx-cols x 24 rows = 408, padded to 416 (13 x K32).
//   k = dxi*24 + r ; dxi = dx+8 in [0,16] ; r = local X row, abs row = yg-8+r.
//   G1 (M=16): m = y_off*2 + pp, pp in {0,1};  G2: m = y_off (p=2), m>=8 zero.
//   A[m][k] = merged[pp][dy+8][dxi], dy = r - 8 - y_off (zero outside [-8,8]).
#define KPAD 416
#define ACH (2 * 16 * KPAD)   // f16 elements per channel (both GEMMs)

__global__ __launch_bounds__(256) void prep_kernel(
    const float* __restrict__ A1, const float* __restrict__ B1,
    const float* __restrict__ A2, const float* __restrict__ B2,
    const float* __restrict__ A3, const float* __restrict__ B3,
    const float* __restrict__ dw_w3, const float* __restrict__ dw_b3,
    const float* __restrict__ w1_3, const float* __restrict__ b1_3,
    const float* __restrict__ w2_3, const float* __restrict__ b2_3,
    const float* __restrict__ dilw3,
    const float* __restrict__ dw_w5, const float* __restrict__ dw_b5,
    const float* __restrict__ w1_5, const float* __restrict__ b1_5,
    const float* __restrict__ w2_5, const float* __restrict__ b2_5,
    const float* __restrict__ dilw5,
    const float* __restrict__ dw_w9, const float* __restrict__ dw_b9,
    const float* __restrict__ w1_9, const float* __restrict__ b1_9,
    const float* __restrict__ w2_9, const float* __restrict__ b2_9,
    const float* __restrict__ dilw9,
    _Float16* __restrict__ wA) {
  const int o = blockIdx.x;
  const int tid = threadIdx.x;
  __shared__ float w0[3 * 289];
  __shared__ float merged[3 * 289];
  __shared__ float bufA[3888];
  __shared__ float bufB[3888];

  // weight0[o,c] = A_c[o] (17x4) @ B_c[o] (4x17)
  for (int i = tid; i < 3 * 289; i += 256) {
    const int c = i / 289, rem = i % 289, k = rem / 17, l = rem % 17;
    const float* A = (c == 0 ? A1 : (c == 1 ? A2 : A3)) + o * 68;
    const float* B = (c == 0 ? B1 : (c == 1 ? B2 : B3)) + o * 68;
    float s = 0.f;
    for (int r = 0; r < 4; ++r) s += A[k * 4 + r] * B[r * 17 + l];
    w0[i] = s;
    merged[i] = 0.f;
  }
  __syncthreads();

  {
    BranchP P{3, 4, 48, 64, 12, 5, 3, {4, 5, 7}, dw_w3, dw_b3, w1_3, b1_3, w2_3, b2_3, dilw3};
    run_branch(tid, P, w0, merged, bufA, bufB);
  }
  {
    BranchP P{5, 2, 12, 48, 6, 9, 1, {1, 0, 0}, dw_w5, dw_b5, w1_5, b1_5, w2_5, b2_5, dilw5};
    run_branch(tid, P, w0, merged, bufA, bufB);
  }
  {
    BranchP P{9, 1, 3, 12, 3, 17, 1, {2, 0, 0}, dw_w9, dw_b9, w1_9, b1_9, w2_9, b2_9, dilw9};
    run_branch(tid, P, w0, merged, bufA, bufB);
  }

  // pack A-matrices (f16, RTE) for both GEMMs
  for (int i = tid; i < ACH; i += 256) {
    const int g = i / (16 * KPAD);
    const int m = (i / KPAD) % 16;
    const int k = i % KPAD;
    const int dxi = k / 24, r = k % 24;
    int pp, yo;
    if (g == 0) { pp = m & 1; yo = m >> 1; } else { pp = 2; yo = m; }
    const int dy = r - 8 - yo;
    float val = 0.f;
    if (!(g == 1 && m >= 8) && dy >= -8 && dy <= 8 && dxi <= 16)
      val = merged[pp * 289 + (dy + 8) * 17 + dxi];
    wA[(size_t)o * ACH + i] = (_Float16)val;
  }
}

// ---------------- main conv kernel (MFMA) ----------------
// block: (ygroup, ch, n); 256 threads = 4 waves; each wave: 4 col-tiles of 16.
// Per col-tile: 13 x {ds_read_b128 B-frag; 2 x mfma_f32_16x16x32_f16 (G1,G2)}.
// LDS: Xt[col][r] f16 transposed tile, col 0..279 (halo+pad), r 0..23, pitch 24.
// All b128 LDS accesses 16B-aligned (48B col stride, r0 in {0,8,16}); lane
// unit-index = 3*col mod 8 -> uniform across banks (conflict-free).
__global__ __launch_bounds__(256) void conv_mfma_kernel(
    const float* __restrict__ xin, const _Float16* __restrict__ wA,
    float* __restrict__ out) {
  const int yg = blockIdx.x * 8;   // output row group base (32 groups)
  const int ch = blockIdx.y;
  const int n  = blockIdx.z;
  const int tid = threadIdx.x;

  __shared__ __align__(16) _Float16 Xt[280 * 24];

  const float* xim = xin + ((size_t)(n * 64 + ch)) * 65536;

  // ---- load + transpose + f16-pack: items = 3 r-blocks x 280 cols ----
  for (int i = tid; i < 3 * 280; i += 256) {
    const int rb = i / 280, c = i % 280;
    const int gx = c - 8;
    const bool cok = (gx >= 0 && gx < 256);
    float v[8];
    #pragma unroll
    for (int rr = 0; rr < 8; ++rr) {
      const int gy = yg - 8 + rb * 8 + rr;
      v[rr] = (cok && gy >= 0 && gy < 256) ? xim[gy * 256 + gx] : 0.f;
    }
    uint4 u;
    u.x = __builtin_bit_cast(uint32, __builtin_amdgcn_cvt_pkrtz(v[0], v[1]));
    u.y = __builtin_bit_cast(uint32, __builtin_amdgcn_cvt_pkrtz(v[2], v[3]));
    u.z = __builtin_bit_cast(uint32, __builtin_amdgcn_cvt_pkrtz(v[4], v[5]));
    u.w = __builtin_bit_cast(uint32, __builtin_amdgcn_cvt_pkrtz(v[6], v[7]));
    *(uint4*)&Xt[c * 24 + rb * 8] = u;
  }
  __syncthreads();

  const int lane = tid & 63;
  const int wv = tid >> 6;
  const int row = lane & 15;   // A-row / B-col / C-col lane index
  const int kg = lane >> 4;    // k-slice group (8 k's each)

  // ---- A fragments: load once, reuse across 4 col-tiles ----
  h8 a1[13], a2[13];
  {
    const _Float16* Ab = wA + (size_t)ch * ACH + row * KPAD;
    #pragma unroll
    for (int t = 0; t < 13; ++t) {
      const int k0 = t * 32 + kg * 8;
      a1[t] = __builtin_bit_cast(h8, *(const uint4*)(Ab + k0));
      a2[t] = __builtin_bit_cast(h8, *(const uint4*)(Ab + 16 * KPAD + k0));
    }
  }
  // ---- B-fragment LDS offsets (j0-independent part) ----
  int boff[13];
  #pragma unroll
  for (int t = 0; t < 13; ++t) {
    const int k0 = t * 32 + kg * 8;
    const int dxi = k0 / 24, r0 = k0 - dxi * 24;   // 8 consecutive k stay in one dxi
    boff[t] = (row + dxi) * 24 + r0;
  }

  for (int tt = 0; tt < 4; ++tt) {
    const int j0 = (wv * 4 + tt) * 16;
    const int jb = j0 * 24;
    f4 c1 = {0.f, 0.f, 0.f, 0.f};
    f4 c2 = {0.f, 0.f, 0.f, 0.f};
    #pragma unroll
    for (int t = 0; t < 13; ++t) {
      const h8 b = __builtin_bit_cast(h8, *(const uint4*)&Xt[jb + boff[t]]);
      c1 = __builtin_amdgcn_mfma_f32_16x16x32_f16(a1[t], b, c1, 0, 0, 0);
      c2 = __builtin_amdgcn_mfma_f32_16x16x32_f16(a2[t], b, c2, 0, 0, 0);
    }
    // ---- store: C col = lane&15, C row = kg*4 + reg ----
    const int gx = j0 + row;
    #pragma unroll
    for (int reg = 0; reg < 4; ++reg) {
      const int r = kg * 4 + reg;              // G1 m-row: (y_off, p=r&1)
      const int y1 = yg + (r >> 1);
      out[(((size_t)n * 192 + ch * 3 + (r & 1)) * 256 + y1) * 256 + gx] = c1[reg];
    }
    if (kg < 2) {
      #pragma unroll
      for (int reg = 0; reg < 4; ++reg) {
        const int r = kg * 4 + reg;            // G2 m-row: y_off (p=2), rows 0..7
        out[(((size_t)n * 192 + ch * 3 + 2) * 256 + (yg + r)) * 256 + gx] = c2[reg];
      }
    }
  }
}

// ---------------- launch ----------------
extern "C" void kernel_launch(void* const* d_in, const int* in_sizes, int n_in,
                              void* d_out, int out_size, void* d_ws, size_t ws_size,
                              hipStream_t stream) {
  const float* xin = (const float*)d_in[0];
  const float* A1 = (const float*)d_in[1];
  const float* B1 = (const float*)d_in[2];
  const float* A2 = (const float*)d_in[3];
  const float* B2 = (const float*)d_in[4];
  const float* A3 = (const float*)d_in[5];
  const float* B3 = (const float*)d_in[6];
  const float* dw_w3 = (const float*)d_in[7];
  const float* dw_b3 = (const float*)d_in[8];
  const float* w1_3 = (const float*)d_in[9];
  const float* b1_3 = (const float*)d_in[10];
  const float* w2_3 = (const float*)d_in[11];
  const float* b2_3 = (const float*)d_in[12];
  const float* dilw3 = (const float*)d_in[13];
  const float* dw_w5 = (const float*)d_in[14];
  const float* dw_b5 = (const float*)d_in[15];
  const float* w1_5 = (const float*)d_in[16];
  const float* b1_5 = (const float*)d_in[17];
  const float* w2_5 = (const float*)d_in[18];
  const float* b2_5 = (const float*)d_in[19];
  const float* dilw5 = (const float*)d_in[20];
  const float* dw_w9 = (const float*)d_in[21];
  const float* dw_b9 = (const float*)d_in[22];
  const float* w1_9 = (const float*)d_in[23];
  const float* b1_9 = (const float*)d_in[24];
  const float* w2_9 = (const float*)d_in[25];
  const float* b2_9 = (const float*)d_in[26];
  const float* dilw9 = (const float*)d_in[27];

  _Float16* wA = (_Float16*)d_ws;  // 64 ch * 2 * 16 * 416 f16 = 1,703,936 B

  prep_kernel<<<64, 256, 0, stream>>>(
      A1, B1, A2, B2, A3, B3,
      dw_w3, dw_b3, w1_3, b1_3, w2_3, b2_3, dilw3,
      dw_w5, dw_b5, w1_5, b1_5, w2_5, b2_5, dilw5,
      dw_w9, dw_b9, w1_9, b1_9, w2_9, b2_9, dilw9,
      wA);

  dim3 grid(32, 64, 8);
  conv_mfma_kernel<<<grid, 256, 0, stream>>>(xin, wA, (float*)d_out);
}

// Round 8
// 207.519 us; speedup vs baseline: 1.8414x; 1.4913x over previous
//
#include <hip/hip_runtime.h>
#include <cstddef>

typedef _Float16 h8 __attribute__((ext_vector_type(8)));
typedef float f4 __attribute__((ext_vector_type(4)));
typedef unsigned int uint32;

// ---------------- prep kernel: synthesize merged 17x17 kernels ----------------
struct BranchP {
  int ksz, scale, CIN, HID, COUT, S, nd;
  int dils[3];
  const float *dw_w, *dw_b, *w1, *b1, *w2, *b2, *dilw;
};

__device__ void run_branch(int tid, const BranchP P,
                           const float* w0, float* merged,
                           float* bufA, float* bufB) {
  const int S = P.S, ksz = P.ksz, CIN = P.CIN, HID = P.HID, COUT = P.COUT;
  const int SS = S * S;
  // 1) pad (bottom/right) + pixel_unshuffle (scale==1 -> copy)
  for (int i = tid; i < CIN * SS; i += 256) {
    const int cc = i / SS, rem = i % SS, hh = rem / S, ww = rem % S;
    const int s2 = P.scale * P.scale;
    const int c = cc / s2, r2 = cc % s2, si = r2 / P.scale, sj = r2 % P.scale;
    const int sh = hh * P.scale + si, sw = ww * P.scale + sj;
    bufA[i] = (sh < 17 && sw < 17) ? w0[c * 289 + sh * 17 + sw] : 0.f;
  }
  __syncthreads();
  // 2) depthwise 3x3, pad 1
  for (int i = tid; i < CIN * SS; i += 256) {
    const int ch = i / SS, rem = i % SS, y = rem / S, x = rem % S;
    float acc = P.dw_b[ch];
    for (int u = 0; u < 3; ++u)
      for (int v = 0; v < 3; ++v) {
        const int yy = y + u - 1, xx = x + v - 1;
        if (yy >= 0 && yy < S && xx >= 0 && xx < S)
          acc += bufA[ch * SS + yy * S + xx] * P.dw_w[ch * 9 + u * 3 + v];
      }
    bufB[i] = acc;
  }
  __syncthreads();
  // 3) 1x1 + bias + relu  (bufB -> bufA)
  for (int i = tid; i < HID * SS; i += 256) {
    const int ho = i / SS, rem = i % SS;
    float acc = P.b1[ho];
    for (int ci = 0; ci < CIN; ++ci) acc += bufB[ci * SS + rem] * P.w1[ho * CIN + ci];
    bufA[i] = fmaxf(acc, 0.f);
  }
  __syncthreads();
  // 4) 1x1 + bias  (bufA -> bufB)
  for (int i = tid; i < COUT * SS; i += 256) {
    const int po = i / SS, rem = i % SS;
    float acc = P.b2[po];
    for (int ci = 0; ci < HID; ++ci) acc += bufA[ci * SS + rem] * P.w2[po * HID + ci];
    bufB[i] = acc;
  }
  __syncthreads();
  // 5) bilinear S -> ksz  (bufB -> bufA)
  for (int i = tid; i < COUT * ksz * ksz; i += 256) {
    const int c = i / (ksz * ksz), rem = i % (ksz * ksz), oy = rem / ksz, ox = rem % ksz;
    const float ratio = (float)S / (float)ksz;
    float sy = fminf(fmaxf((oy + 0.5f) * ratio - 0.5f, 0.f), (float)(S - 1));
    float sx = fminf(fmaxf((ox + 0.5f) * ratio - 0.5f, 0.f), (float)(S - 1));
    const int y0 = (int)sy; const int y1 = min(y0 + 1, S - 1); const float ty = sy - (float)y0;
    const int x0 = (int)sx; const int x1 = min(x0 + 1, S - 1); const float tx = sx - (float)x0;
    const float* img = bufB + c * SS;
    const float top = img[y0 * S + x0] * (1.f - tx) + img[y0 * S + x1] * tx;
    const float bot = img[y1 * S + x0] * (1.f - tx) + img[y1 * S + x1] * tx;
    bufA[i] = top * (1.f - ty) + bot * ty;
  }
  __syncthreads();
  // 6) per-dil channel mix + zero-interleave + accumulate into merged
  for (int di = 0; di < P.nd; ++di) {
    const int d = P.dils[di];
    const int e = d * (ksz - 1) + 1, pp = 8 - e / 2;
    for (int i = tid; i < 3 * ksz * ksz; i += 256) {
      const int p = i / (ksz * ksz), rem = i % (ksz * ksz), ih = rem / ksz, iw = rem % ksz;
      float acc = 0.f;
      for (int c2 = 0; c2 < COUT; ++c2)
        acc += bufA[c2 * ksz * ksz + rem] * P.dilw[(di * 3 + p) * COUT + c2];
      merged[p * 289 + (pp + d * ih) * 17 + (pp + d * iw)] += acc;
    }
  }
  __syncthreads();
}

// A-matrix geometry: K = 17 dx-cols x 24 rows = 408, padded to 416 (13 x K32).
//   k = dxi*24 + r ; dxi = dx+8 in [0,16] ; r = local X row (rel. to ygroup base).
//   G1 (M=16): m = y_off*2 + pp, pp in {0,1};  G2: m = y_off (p=2), m>=8 zero.
//   A[m][k] = merged[pp][dy+8][dxi], dy = r - 8 - y_off (zero outside [-8,8]).
#define KPAD 416
#define ACH (2 * 16 * KPAD)   // f16 elements per channel (both GEMMs)

__global__ __launch_bounds__(256) void prep_kernel(
    const float* __restrict__ A1, const float* __restrict__ B1,
    const float* __restrict__ A2, const float* __restrict__ B2,
    const float* __restrict__ A3, const float* __restrict__ B3,
    const float* __restrict__ dw_w3, const float* __restrict__ dw_b3,
    const float* __restrict__ w1_3, const float* __restrict__ b1_3,
    const float* __restrict__ w2_3, const float* __restrict__ b2_3,
    const float* __restrict__ dilw3,
    const float* __restrict__ dw_w5, const float* __restrict__ dw_b5,
    const float* __restrict__ w1_5, const float* __restrict__ b1_5,
    const float* __restrict__ w2_5, const float* __restrict__ b2_5,
    const float* __restrict__ dilw5,
    const float* __restrict__ dw_w9, const float* __restrict__ dw_b9,
    const float* __restrict__ w1_9, const float* __restrict__ b1_9,
    const float* __restrict__ w2_9, const float* __restrict__ b2_9,
    const float* __restrict__ dilw9,
    _Float16* __restrict__ wA) {
  const int o = blockIdx.x;
  const int tid = threadIdx.x;
  __shared__ float w0[3 * 289];
  __shared__ float merged[3 * 289];
  __shared__ float bufA[3888];
  __shared__ float bufB[3888];

  // weight0[o,c] = A_c[o] (17x4) @ B_c[o] (4x17)
  for (int i = tid; i < 3 * 289; i += 256) {
    const int c = i / 289, rem = i % 289, k = rem / 17, l = rem % 17;
    const float* A = (c == 0 ? A1 : (c == 1 ? A2 : A3)) + o * 68;
    const float* B = (c == 0 ? B1 : (c == 1 ? B2 : B3)) + o * 68;
    float s = 0.f;
    for (int r = 0; r < 4; ++r) s += A[k * 4 + r] * B[r * 17 + l];
    w0[i] = s;
    merged[i] = 0.f;
  }
  __syncthreads();

  {
    BranchP P{3, 4, 48, 64, 12, 5, 3, {4, 5, 7}, dw_w3, dw_b3, w1_3, b1_3, w2_3, b2_3, dilw3};
    run_branch(tid, P, w0, merged, bufA, bufB);
  }
  {
    BranchP P{5, 2, 12, 48, 6, 9, 1, {1, 0, 0}, dw_w5, dw_b5, w1_5, b1_5, w2_5, b2_5, dilw5};
    run_branch(tid, P, w0, merged, bufA, bufB);
  }
  {
    BranchP P{9, 1, 3, 12, 3, 17, 1, {2, 0, 0}, dw_w9, dw_b9, w1_9, b1_9, w2_9, b2_9, dilw9};
    run_branch(tid, P, w0, merged, bufA, bufB);
  }

  // pack A-matrices (f16, RTE) for both GEMMs
  for (int i = tid; i < ACH; i += 256) {
    const int g = i / (16 * KPAD);
    const int m = (i / KPAD) % 16;
    const int k = i % KPAD;
    const int dxi = k / 24, r = k % 24;
    int pp, yo;
    if (g == 0) { pp = m & 1; yo = m >> 1; } else { pp = 2; yo = m; }
    const int dy = r - 8 - yo;
    float val = 0.f;
    if (!(g == 1 && m >= 8) && dy >= -8 && dy <= 8 && dxi <= 16)
      val = merged[pp * 289 + (dy + 8) * 17 + dxi];
    wA[(size_t)o * ACH + i] = (_Float16)val;
  }
}

// ---------------- main conv kernel (MFMA, 32 out-rows/block) ----------------
// block: (ygroup4, ch, n); 256 threads = 4 waves. Block covers 32 output rows
// (4 y-groups of 8) x 256 cols. Wave: 4 col-tiles x 4 y-groups = 16 units,
// processed as col-tile PAIRS -> 4 independent MFMA chains in flight.
// LDS: Xt[col][r], col 0..279 (halo), r 0..47, pitch 56 f16 (112 B).
//   b128 lane reads: byte-unit = 7*col mod 8 -> 2 lanes/16B-unit (free).
// A fragments: loaded once per block (26 x uint4/lane), reused 16x.
__global__ __launch_bounds__(256) void conv_mfma_kernel(
    const float* __restrict__ xin, const _Float16* __restrict__ wA,
    float* __restrict__ out) {
  const int yg = blockIdx.x * 32;  // output row base (8 blocks -> 256 rows)
  const int ch = blockIdx.y;
  const int n  = blockIdx.z;
  const int tid = threadIdx.x;

#define PITCH 56
  __shared__ __align__(16) _Float16 Xt[280 * PITCH];  // 31,360 B

  const float* xim = xin + ((size_t)(n * 64 + ch)) * 65536;

  const int lane = tid & 63;
  const int wv = tid >> 6;
  const int row = lane & 15;   // A-row / B-col / C-col lane index
  const int kg = lane >> 4;    // k-slice group (8 k's each)

  // ---- A fragments first (independent global loads; reused all block) ----
  h8 a1[13], a2[13];
  {
    const _Float16* Ab = wA + (size_t)ch * ACH + row * KPAD;
    #pragma unroll
    for (int t = 0; t < 13; ++t) {
      const int k0 = t * 32 + kg * 8;
      a1[t] = __builtin_bit_cast(h8, *(const uint4*)(Ab + k0));
      a2[t] = __builtin_bit_cast(h8, *(const uint4*)(Ab + 16 * KPAD + k0));
    }
  }

  // ---- load + transpose + f16-pack tile: 6 r-blocks x 280 cols ----
  for (int i = tid; i < 6 * 280; i += 256) {
    const int rb = i / 280, c = i % 280;
    const int gx = c - 8;
    const bool cok = (gx >= 0 && gx < 256);
    float v[8];
    #pragma unroll
    for (int rr = 0; rr < 8; ++rr) {
      const int gy = yg - 8 + rb * 8 + rr;
      v[rr] = (cok && gy >= 0 && gy < 256) ? xim[gy * 256 + gx] : 0.f;
    }
    uint4 u;
    u.x = __builtin_bit_cast(uint32, __builtin_amdgcn_cvt_pkrtz(v[0], v[1]));
    u.y = __builtin_bit_cast(uint32, __builtin_amdgcn_cvt_pkrtz(v[2], v[3]));
    u.z = __builtin_bit_cast(uint32, __builtin_amdgcn_cvt_pkrtz(v[4], v[5]));
    u.w = __builtin_bit_cast(uint32, __builtin_amdgcn_cvt_pkrtz(v[6], v[7]));
    *(uint4*)&Xt[c * PITCH + rb * 8] = u;
  }
  __syncthreads();

  // ---- B-fragment LDS offsets (ygroup/coltile-independent part) ----
  int boff[13];
  #pragma unroll
  for (int t = 0; t < 13; ++t) {
    const int k0 = t * 32 + kg * 8;
    const int dxi = k0 / 24, r0 = k0 - dxi * 24;   // 8 consecutive k in one dxi
    boff[t] = (row + dxi) * PITCH + r0;
  }

  // ---- 8 unit-pairs: (ygroup g, col-pair cp) ----
  for (int pr = 0; pr < 8; ++pr) {
    const int g = pr >> 1, cp = pr & 1;
    const int j0a = (wv * 4 + cp * 2) * 16;       // first col-tile of the pair
    const int ba = j0a * PITCH + 8 * g;
    const int bb = ba + 16 * PITCH;
    f4 c1a = {0.f, 0.f, 0.f, 0.f}, c2a = {0.f, 0.f, 0.f, 0.f};
    f4 c1b = {0.f, 0.f, 0.f, 0.f}, c2b = {0.f, 0.f, 0.f, 0.f};
    #pragma unroll
    for (int t = 0; t < 13; ++t) {
      const h8 vba = __builtin_bit_cast(h8, *(const uint4*)&Xt[ba + boff[t]]);
      const h8 vbb = __builtin_bit_cast(h8, *(const uint4*)&Xt[bb + boff[t]]);
      c1a = __builtin_amdgcn_mfma_f32_16x16x32_f16(a1[t], vba, c1a, 0, 0, 0);
      c1b = __builtin_amdgcn_mfma_f32_16x16x32_f16(a1[t], vbb, c1b, 0, 0, 0);
      c2a = __builtin_amdgcn_mfma_f32_16x16x32_f16(a2[t], vba, c2a, 0, 0, 0);
      c2b = __builtin_amdgcn_mfma_f32_16x16x32_f16(a2[t], vbb, c2b, 0, 0, 0);
    }
    // ---- store: C col = lane&15, C row = kg*4 + reg ----
    const int ygg = yg + 8 * g;
    #pragma unroll
    for (int half = 0; half < 2; ++half) {
      const int gx = j0a + half * 16 + row;
      const f4 s1 = half ? c1b : c1a;
      const f4 s2 = half ? c2b : c2a;
      #pragma unroll
      for (int reg = 0; reg < 4; ++reg) {
        const int r = kg * 4 + reg;            // G1 m-row: (y_off, p=r&1)
        out[(((size_t)n * 192 + ch * 3 + (r & 1)) * 256 + (ygg + (r >> 1))) * 256 + gx] = s1[reg];
      }
      if (kg < 2) {
        #pragma unroll
        for (int reg = 0; reg < 4; ++reg) {
          const int r = kg * 4 + reg;          // G2 m-row: y_off (p=2), rows 0..7
          out[(((size_t)n * 192 + ch * 3 + 2) * 256 + (ygg + r)) * 256 + gx] = s2[reg];
        }
      }
    }
  }
#undef PITCH
}

// ---------------- launch ----------------
extern "C" void kernel_launch(void* const* d_in, const int* in_sizes, int n_in,
                              void* d_out, int out_size, void* d_ws, size_t ws_size,
                              hipStream_t stream) {
  const float* xin = (const float*)d_in[0];
  const float* A1 = (const float*)d_in[1];
  const float* B1 = (const float*)d_in[2];
  const float* A2 = (const float*)d_in[3];
  const float* B2 = (const float*)d_in[4];
  const float* A3 = (const float*)d_in[5];
  const float* B3 = (const float*)d_in[6];
  const float* dw_w3 = (const float*)d_in[7];
  const float* dw_b3 = (const float*)d_in[8];
  const float* w1_3 = (const float*)d_in[9];
  const float* b1_3 = (const float*)d_in[10];
  const float* w2_3 = (const float*)d_in[11];
  const float* b2_3 = (const float*)d_in[12];
  const float* dilw3 = (const float*)d_in[13];
  const float* dw_w5 = (const float*)d_in[14];
  const float* dw_b5 = (const float*)d_in[15];
  const float* w1_5 = (const float*)d_in[16];
  const float* b1_5 = (const float*)d_in[17];
  const float* w2_5 = (const float*)d_in[18];
  const float* b2_5 = (const float*)d_in[19];
  const float* dilw5 = (const float*)d_in[20];
  const float* dw_w9 = (const float*)d_in[21];
  const float* dw_b9 = (const float*)d_in[22];
  const float* w1_9 = (const float*)d_in[23];
  const float* b1_9 = (const float*)d_in[24];
  const float* w2_9 = (const float*)d_in[25];
  const float* b2_9 = (const float*)d_in[26];
  const float* dilw9 = (const float*)d_in[27];

  _Float16* wA = (_Float16*)d_ws;  // 64 ch * 2 * 16 * 416 f16 = 1,703,936 B

  prep_kernel<<<64, 256, 0, stream>>>(
      A1, B1, A2, B2, A3, B3,
      dw_w3, dw_b3, w1_3, b1_3, w2_3, b2_3, dilw3,
      dw_w5, dw_b5, w1_5, b1_5, w2_5, b2_5, dilw5,
      dw_w9, dw_b9, w1_9, b1_9, w2_9, b2_9, dilw9,
      wA);

  dim3 grid(8, 64, 8);
  conv_mfma_kernel<<<grid, 256, 0, stream>>>(xin, wA, (float*)d_out);
}